// Round 13
// baseline (3930.437 us; speedup 1.0000x reference)
//
#include <hip/hip_runtime.h>
#include <hip/hip_bf16.h>

// LSTM decoder: B=512, H=1024, NCHAR=128, T=256.
// Round 13 = round-12 (PASSED, 3777us) + two release/acquire overhauls:
//  (a) coalesced h stores: cell results transpose through LDS htile[128][24],
//      then 256 threads issue ONE global_store_dwordx4 sc1 each (256 wide
//      write-through stores/block vs 2048 u32 atomics in r11/r12).
//  (b) acquire relay collapsed: elected last-arriver per XCD does
//      buffer_inv sc1 (L1+L2 inv, the LLVM agent-acquire op) BEFORE its
//      relaxed gCnt add -> any spinner seeing gCnt at target is ordered
//      after its XCD's L2 inv. Epoch relay deleted; all blocks spin gCnt
//      directly (r7-proven). Per-block stale L1 handled by a cheap sc-less
//      buffer_inv each step (off the dependent chain).
// Census degenerate -> conservative all-fence fallback (r6 semantics).
// Out-GEMM shadow / reduce / flush / census: byte-for-byte r12.

using bf16 = __hip_bfloat16;
typedef short bf16x8 __attribute__((ext_vector_type(8)));
typedef float f32x4  __attribute__((ext_vector_type(4)));
typedef float f32x16 __attribute__((ext_vector_type(16)));

static constexpr int BATCH = 512;
static constexpr int HID   = 1024;
static constexpr int NCH   = 128;
static constexpr int TLEN  = 256;
static constexpr int NP    = 4096;   // 4*HID

// workspace byte offsets
static constexpr size_t OFF_WP  = 0;                                // bf16 [4096][1024] fused W, rows permuted
static constexpr size_t OFF_WOB = OFF_WP  + (size_t)NP * HID * 2;   // bf16 [128][1024]
static constexpr size_t OFF_HB0 = OFF_WOB + (size_t)NCH * HID * 2;  // bf16 h buffer 0
static constexpr size_t OFF_HB1 = OFF_HB0 + (size_t)BATCH * HID * 2;
static constexpr size_t OFF_XP  = OFF_HB1 + (size_t)BATCH * HID * 2; // f32 [512][4096] x_part permuted
static constexpr size_t OFF_BAR = OFF_XP  + (size_t)BATCH * NP * 4;
// bar layout (u32 index; prep_misc zeroes [0,1024)):
//   [x*32]      x<8 : per-XCD population census
//   [8*32]          : census completion counter
//   [(16+x)*32] x<8 : per-XCD per-step arrival counters (monotone)
//   [24*32]         : global step counter gCnt (monotone)

__device__ __forceinline__ float sigm(float x) { return 1.f / (1.f + __expf(-x)); }

// permuted gate-row index: row' = (j>>4)*64 + gate*16 + (j&15); decode n = gate*H + j
__device__ __forceinline__ int rowp_to_n(int rp) {
  int jg = rp >> 6, c = rp & 63;
  return (c >> 4) * HID + jg * 16 + (c & 15);
}

__global__ void prep_misc(const float* __restrict__ hid0, const float* __restrict__ wout,
                          bf16* __restrict__ hb0, bf16* __restrict__ wob,
                          unsigned* __restrict__ bar)
{
  int gid = blockIdx.x * blockDim.x + threadIdx.x;
  int stride = gridDim.x * blockDim.x;
  for (int i = gid; i < BATCH * HID; i += stride) hb0[i] = __float2bfloat16(hid0[i]);
  for (int i = gid; i < NCH * HID;  i += stride) wob[i] = __float2bfloat16(wout[i]);
  if (gid < 1024) bar[gid] = 0u;
}

__global__ void prep_wp(const float* __restrict__ W_ih, const float* __restrict__ W_hh,
                        bf16* __restrict__ wp)
{
  int gid = blockIdx.x * blockDim.x + threadIdx.x;
  int stride = gridDim.x * blockDim.x;
  for (int i = gid; i < NP * HID; i += stride) {
    int rp = i >> 10, k = i & 1023;
    int n = rowp_to_n(rp);
    float v = W_ih[(size_t)n * 1152 + 128 + k] + W_hh[(size_t)n * 1024 + k];
    wp[i] = __float2bfloat16(v);
  }
}

__global__ void prep_xp(const float* __restrict__ inp0, const float* __restrict__ W_ih,
                        const float* __restrict__ b_ih, const float* __restrict__ b_hh,
                        float* __restrict__ xp)
{
  int b = blockIdx.x;
  const float4* ip = (const float4*)(inp0 + b * NCH);
  for (int rp = threadIdx.x; rp < NP; rp += blockDim.x) {
    int n = rowp_to_n(rp);
    const float4* wr = (const float4*)(W_ih + (size_t)n * 1152);
    float acc = b_ih[n] + b_hh[n];
    #pragma unroll 8
    for (int q = 0; q < 32; ++q) {
      float4 a = ip[q], w = wr[q];
      acc += a.x * w.x + a.y * w.y + a.z * w.z + a.w * w.w;
    }
    xp[(size_t)b * NP + rp] = acc;
  }
}

__launch_bounds__(256, 1)
__global__ void lstm_main(const bf16* __restrict__ wp, const bf16* __restrict__ wob,
                          const float* __restrict__ xp, const float* __restrict__ cell0,
                          const float* __restrict__ bout,
                          bf16* __restrict__ hb0, bf16* __restrict__ hb1,
                          float* __restrict__ out, unsigned* __restrict__ bar)
{
  __shared__ bf16 wlds[64 * HID];        // 128 KB, xor-swizzled (4 row bits)
  __shared__ float obuf[16][16][17];     // out tile x 16 buffered steps (+1 pad)
  __shared__ float opart[3][16][16];     // waves 1-3 out-GEMM partials (split-K)
  __shared__ bf16 htile[128][24];        // h transpose tile (row stride 48B, 16B-aligned)
  __shared__ int s_pop[8];

  const int tid  = threadIdx.x;
  const int bx   = blockIdx.x;
  const int lane = tid & 63;
  const int wv   = tid >> 6;        // wave 0..3 (rows)
  const int bm   = bx >> 6;         // batch group 0..3 (128 rows)
  const int jg   = bx & 63;         // j group (16 h-cols -> 64 gate rows)
  const int wrow = bm * 128 + wv * 32;
  const int l31  = lane & 31;
  const int lhi  = lane >> 5;
  const bool low = (l31 < 16);
  const int jj   = lane & 15;
  const int jcol = jg * 16 + jj;

  // stage fused-W slice into LDS (swizzled: byte ^= (row&15)<<4)
  {
    const char* src = (const char*)(wp + (size_t)jg * 64 * HID);
    for (int it = tid; it < 8192; it += 256) {
      int r  = it >> 7;
      int kb = (it & 127) << 4;
      bf16x8 v = *(const bf16x8*)(src + r * 2048 + kb);
      *(bf16x8*)((char*)wlds + r * 2048 + (kb ^ ((r & 15) << 4))) = v;
    }
  }

  // x_part -> registers (constant acc init; C layout: col=lane&31, row=(q&3)+8*(q>>2)+4*lhi)
  f32x16 xpA, xpB;
  #pragma unroll
  for (int q = 0; q < 16; ++q) {
    int rr = (q & 3) + ((q >> 2) << 3) + (lhi << 2);
    const float* xr = xp + (size_t)(wrow + rr) * NP + jg * 64;
    xpA[q] = xr[l31];
    xpB[q] = xr[32 + l31];
  }

  // cell state -> registers. low half-lanes own rows {0-3,8-11}+4*lhi, high own +16.
  float creg[8];
  #pragma unroll
  for (int q = 0; q < 8; ++q) {
    int rr = (q & 3) + ((q >> 2) << 3) + (lhi << 2) + (low ? 0 : 16);
    creg[q] = cell0[(size_t)(wrow + rr) * HID + jcol];
  }

  const int omt = (bx >> 3) << 4;   // out-tile batch row base (subset of own bm panel)
  const int ont = (bx & 7) << 4;    // out-tile char col base (8 tiles of 16)
  const float bo = bout[ont + jj];  // jj == tid&15, reused by the reduce

  // packing-store geometry: thread -> (row, 16B half-row)
  const int prow  = tid >> 1;       // 0..127 (panel row)
  const int phalf = tid & 1;        // 0/1
  char* const pdst0 = (char*)0 + ((size_t)(bm * 128 + prow) * HID + jg * 16 + phalf * 8) * 2;

  // ---- one-time census: physical XCD id + per-XCD block population
  const int myx = __builtin_amdgcn_s_getreg(6164) & 7;  // HW_REG_XCC_ID (id=20,off=0,sz=4)
  if (tid == 0) {
    __hip_atomic_fetch_add(bar + (size_t)myx * 32, 1u, __ATOMIC_RELAXED, __HIP_MEMORY_SCOPE_AGENT);
    __threadfence();   // order pop-add before census-completion add
    __hip_atomic_fetch_add(bar + (size_t)8 * 32, 1u, __ATOMIC_RELEASE, __HIP_MEMORY_SCOPE_AGENT);
    int it = 0;
    while (__hip_atomic_load(bar + (size_t)8 * 32, __ATOMIC_RELAXED, __HIP_MEMORY_SCOPE_AGENT) < 256u) {
      __builtin_amdgcn_s_sleep(1);
      if ((++it & 255) == 0) __builtin_amdgcn_fence(__ATOMIC_ACQUIRE, "agent");
    }
  }
  __syncthreads();
  if (tid < 8)
    s_pop[tid] = (int)__hip_atomic_load(bar + (size_t)tid * 32, __ATOMIC_RELAXED, __HIP_MEMORY_SCOPE_AGENT);
  __syncthreads();
  int nx = 0, tot = 0;
  #pragma unroll
  for (int i = 0; i < 8; ++i) { nx += (s_pop[i] != 0) ? 1 : 0; tot += s_pop[i]; }
  const bool elect = (nx >= 2) && (tot == 256);   // degenerate -> all-fence fallback
  const unsigned mypop = (unsigned)s_pop[myx];
  const unsigned NF = elect ? (unsigned)nx : 256u;
  unsigned* const xcdCnt = bar + (size_t)(16 + myx) * 32;
  unsigned* const gCnt   = bar + (size_t)24 * 32;

  __syncthreads();

  // iter t: gates+store h_{t+1} (t<256) -> arrival (elected: L2 inv + gCnt)
  //   -> [out GEMM step t-1 on waves 1-3 || gCnt spin on tid0] -> reduce.
  for (int t = 0; t <= TLEN + 1; ++t) {
    const bf16* __restrict__ hcur = (t & 1) ? hb1 : hb0;
    bf16* __restrict__ hnxt = (t & 1) ? hb0 : hb1;

    // ---- flush 16 buffered output steps (t-17..t-2), one iter delayed
    if (t >= 17 && ((t - 17) & 15) == 0) {
      const int orow = tid >> 4, ocol = tid & 15;
      float* dst = out + ((size_t)(omt + orow) * NCH + (ont + ocol)) * TLEN + (t - 17);
      #pragma unroll
      for (int s = 0; s < 16; ++s) dst[s] = obuf[orow][ocol][s];
    }

    if (t < TLEN) {
      // ---- gates GEMM: [128x64] = x_part + h_t[128x1024] @ W'[64x1024]^T
      f32x16 accA = xpA, accB = xpB;
      {
        const bf16* ap = hcur + (size_t)(wrow + l31) * HID + (lhi << 3);
        const char* wb = (const char*)wlds;
        const int base0 = l31 * 2048;
        const int sxor  = (l31 & 15) << 4;
        const int kb4   = lhi << 4;
        #pragma unroll 16
        for (int ks = 0; ks < 64; ++ks) {
          bf16x8 av = *(const bf16x8*)(ap + ks * 16);
          const int ko = ((ks << 5) | kb4) ^ sxor;
          bf16x8 b0 = *(const bf16x8*)(wb + base0 + ko);
          bf16x8 b1 = *(const bf16x8*)(wb + base0 + 65536 + ko);
          accA = __builtin_amdgcn_mfma_f32_32x32x16_bf16(av, b0, accA, 0, 0, 0);
          accB = __builtin_amdgcn_mfma_f32_32x32x16_bf16(av, b1, accB, 0, 0, 0);
        }
      }

      // ---- LSTM cell update. accA: i(l31<16)/f; accB: g/o.
      float s0[16], s1[16], u0[16], u1[16];
      #pragma unroll
      for (int q = 0; q < 16; ++q) {
        s0[q] = sigm(accA[q]);
        float a1 = accB[q];
        float sg = sigm(low ? 2.f * a1 : a1);
        s1[q] = low ? 2.f * sg - 1.f : sg;
      }
      #pragma unroll
      for (int q = 0; q < 16; ++q) {
        u0[q] = __shfl_xor(s0[q], 16);
        u1[q] = __shfl_xor(s1[q], 16);
      }
      #pragma unroll
      for (int q = 0; q < 8; ++q) {
        float fg  = low ? u0[q]         : s0[q + 8];
        float ig  = low ? s0[q] * s1[q] : u0[q + 8] * u1[q + 8];
        float og  = low ? u1[q]         : s1[q + 8];
        float cn  = fg * creg[q] + ig;
        creg[q] = cn;
        float hv = og * (2.f * sigm(2.f * cn) - 1.f);
        int rr = (q & 3) + ((q >> 2) << 3) + (lhi << 2) + (low ? 0 : 16);
        htile[wv * 32 + rr][jj] = __float2bfloat16(hv);   // transpose via LDS
      }
      __syncthreads();

      // ---- coalesced h store: 256 x global_store_dwordx4 sc1 (LLC write-through)
      {
        bf16x8 vv = *(const bf16x8*)(&htile[prow][phalf * 8]);
        char* dst = (char*)hnxt + (size_t)(pdst0 - (char*)0);
        asm volatile("global_store_dwordx4 %0, %1, off sc1" :: "v"(dst), "v"(vv) : "memory");
      }
      asm volatile("s_waitcnt vmcnt(0)" ::: "memory");
      __syncthreads();

      // ---- release + elected full-inv: arrival add; last arriver on XCD does
      //      buffer_inv sc1 (L1+L2 inv; all mates' reads done by arrival order)
      //      then relaxed gCnt add -> spinners seeing gCnt are post-inv.
      if (tid == 0) {
        unsigned old = __hip_atomic_fetch_add(xcdCnt, 1u, __ATOMIC_RELAXED, __HIP_MEMORY_SCOPE_AGENT);
        const bool lastx = elect && (old == mypop * (unsigned)(t + 1) - 1u);
        if (lastx) {
          asm volatile("buffer_inv sc1\n\ts_waitcnt vmcnt(0)" ::: "memory");
          __hip_atomic_fetch_add(gCnt, 1u, __ATOMIC_RELAXED, __HIP_MEMORY_SCOPE_AGENT);
        } else if (!elect) {
          __threadfence();   // degenerate-census fallback: conservative
          __hip_atomic_fetch_add(gCnt, 1u, __ATOMIC_RELEASE, __HIP_MEMORY_SCOPE_AGENT);
        }
      }
      // per-block stale-L1 drop (cheap, off the dependent chain). Wipes last
      // iter's out-GEMM refills of the buffer rewritten this iter.
      if (elect && wv == 0) asm volatile("buffer_inv" ::: "memory");
    }

    // ---- out GEMM for step t-1 (h_t, warm rows): waves 1-3, 3-way split-K
    if (t >= 1 && t <= TLEN && wv > 0) {
      f32x4 oacc = {0.f, 0.f, 0.f, 0.f};
      const int kq = (lane >> 4) << 3;
      const bf16* ap2 = hcur + (size_t)(omt + jj) * HID + kq;
      const bf16* bp2 = wob + (size_t)(ont + jj) * HID + kq;
      const int k0 = (wv - 1) * 11;
      const int k1 = (k0 + 11 < 32) ? k0 + 11 : 32;
      #pragma unroll 4
      for (int ks = k0; ks < k1; ++ks) {
        bf16x8 avv = *(const bf16x8*)(ap2 + ks * 32);
        bf16x8 bvv = *(const bf16x8*)(bp2 + ks * 32);
        oacc = __builtin_amdgcn_mfma_f32_16x16x32_bf16(avv, bvv, oacc, 0, 0, 0);
      }
      #pragma unroll
      for (int q = 0; q < 4; ++q)
        opart[wv - 1][((lane >> 4) << 2) + q][jj] = oacc[q];
    }

    // ---- concurrently: tid0 spins on gCnt (no fences needed in elect mode)
    if (t < TLEN && tid == 0) {
      const unsigned tgt = NF * (unsigned)(t + 1);
      int it = 0;
      while (__hip_atomic_load(gCnt, __ATOMIC_RELAXED, __HIP_MEMORY_SCOPE_AGENT) < tgt) {
        __builtin_amdgcn_s_sleep(1);
        if ((++it & 1023) == 0) __builtin_amdgcn_fence(__ATOMIC_ACQUIRE, "agent");
      }
    }
    if (t < TLEN && !elect && tid < 64) __builtin_amdgcn_fence(__ATOMIC_ACQUIRE, "agent");
    __syncthreads();

    // ---- reduce 3 partials -> obuf slot (t-1)&15
    if (t >= 1 && t <= TLEN) {
      const int orow = tid >> 4, ocol = tid & 15;
      float s = opart[0][orow][ocol] + opart[1][orow][ocol] + opart[2][orow][ocol];
      obuf[orow][ocol][(t - 1) & 15] = s + bo;
    }
    __syncthreads();   // protects opart/htile reuse across iterations
  }
}

extern "C" void kernel_launch(void* const* d_in, const int* in_sizes, int n_in,
                              void* d_out, int out_size, void* d_ws, size_t ws_size,
                              hipStream_t stream)
{
  const float* hid0  = (const float*)d_in[0];
  const float* inp0  = (const float*)d_in[1];
  const float* cell0 = (const float*)d_in[2];
  const float* W_ih  = (const float*)d_in[3];
  const float* W_hh  = (const float*)d_in[4];
  const float* b_ih  = (const float*)d_in[5];
  const float* b_hh  = (const float*)d_in[6];
  const float* W_out = (const float*)d_in[7];
  const float* b_out = (const float*)d_in[8];
  float* out = (float*)d_out;

  char* ws = (char*)d_ws;
  bf16* wp      = (bf16*)(ws + OFF_WP);
  bf16* wob     = (bf16*)(ws + OFF_WOB);
  bf16* hb0     = (bf16*)(ws + OFF_HB0);
  bf16* hb1     = (bf16*)(ws + OFF_HB1);
  float* xp     = (float*)(ws + OFF_XP);
  unsigned* bar = (unsigned*)(ws + OFF_BAR);

  prep_misc<<<512, 256, 0, stream>>>(hid0, W_out, hb0, wob, bar);
  prep_wp<<<4096, 256, 0, stream>>>(W_ih, W_hh, wp);
  prep_xp<<<512, 256, 0, stream>>>(inp0, W_ih, b_ih, b_hh, xp);

  void* args[] = { &wp, &wob, &xp, &cell0, &b_out, &hb0, &hb1, &out, &bar };
  hipError_t e = hipLaunchCooperativeKernel(lstm_main, dim3(256), dim3(256), args, 0u, stream);
  if (e != hipSuccess) {
    lstm_main<<<dim3(256), dim3(256), 0, stream>>>(wp, wob, xp, cell0, b_out,
                                                   hb0, hb1, out, bar);
  }
}

// Round 14
// 3658.834 us; speedup vs baseline: 1.0742x; 1.0742x over previous
//
#include <hip/hip_runtime.h>
#include <hip/hip_bf16.h>

// LSTM decoder: B=512, H=1024, NCHAR=128, T=256.
// Round 14 = round-11 (PASSED, 3765us = best; r12/r13 attacks on the barrier
// instruction sequence were flat/negative) + ONE structural change: the grid
// barrier splits into 4 INDEPENDENT per-bm-group barriers (64 blocks each).
// Block (bm,jg) only ever touches h rows [bm*128, bm*128+128) -- written by
// its own group -- so groups share nothing but read-only W. Global sync was
// coupling max-over-256 jitter; per-group sync is max-over-64 and groups
// drift to absorb transients.
// Protocol per group g (r11-proven primitives):
//   release: packed-u32 sc1 RELAXED atomic h stores (write-through, no dirty
//     L2) -> vmcnt drain -> sync -> relaxed (g,XCD) arrival add; LAST arriver
//     of (g,x) adds gCnt[g] RELAXED (no fence needed: its RMW followed all
//     mates' LLC-visible stores).
//   acquire: that same elected block polls gCnt[g] to nxg*(t+1), does ONE
//     agent acquire fence (XCD L2+L1 inv), publishes epoch[g][x] (relaxed
//     agent atomic); group-mates on (g,x) spin on epoch then L1 buffer_inv.
//     Bounded timeout -> poll gCnt[g] + full threadfence (conservative).
// Census degenerate (group pop != 64) -> per-group all-fence fallback (r6).

using bf16 = __hip_bfloat16;
typedef short bf16x8 __attribute__((ext_vector_type(8)));
typedef float f32x4  __attribute__((ext_vector_type(4)));
typedef float f32x16 __attribute__((ext_vector_type(16)));

static constexpr int BATCH = 512;
static constexpr int HID   = 1024;
static constexpr int NCH   = 128;
static constexpr int TLEN  = 256;
static constexpr int NP    = 4096;   // 4*HID

// workspace byte offsets
static constexpr size_t OFF_WP  = 0;                                // bf16 [4096][1024] fused W, rows permuted
static constexpr size_t OFF_WOB = OFF_WP  + (size_t)NP * HID * 2;   // bf16 [128][1024]
static constexpr size_t OFF_HB0 = OFF_WOB + (size_t)NCH * HID * 2;  // bf16 h buffer 0
static constexpr size_t OFF_HB1 = OFF_HB0 + (size_t)BATCH * HID * 2;
static constexpr size_t OFF_XP  = OFF_HB1 + (size_t)BATCH * HID * 2; // f32 [512][4096] x_part permuted
static constexpr size_t OFF_BAR = OFF_XP  + (size_t)BATCH * NP * 4;
// bar layout (u32 index, stride 32 = 128B; prep_misc zeroes [0,4096)):
//   [(g*8+x)*32]        g<4,x<8 : per-(group,XCD) population census
//   [32*32]                     : census completion counter (to 256)
//   [(40+g*8+x)*32]     g<4,x<8 : per-(group,XCD) arrival counters (monotone)
//   [(80+g)*32]         g<4     : per-group step counters gCnt[g] (monotone)
//   [(96+g*8+x)*32]     g<4,x<8 : per-(group,XCD) epoch words

__device__ __forceinline__ float sigm(float x) { return 1.f / (1.f + __expf(-x)); }

__device__ __forceinline__ unsigned short f2bf(float x) {
  unsigned u = __float_as_uint(x);
  return (unsigned short)((u + 0x7FFFu + ((u >> 16) & 1u)) >> 16);
}

// permuted gate-row index: row' = (j>>4)*64 + gate*16 + (j&15); decode n = gate*H + j
__device__ __forceinline__ int rowp_to_n(int rp) {
  int jg = rp >> 6, c = rp & 63;
  return (c >> 4) * HID + jg * 16 + (c & 15);
}

__global__ void prep_misc(const float* __restrict__ hid0, const float* __restrict__ wout,
                          bf16* __restrict__ hb0, bf16* __restrict__ wob,
                          unsigned* __restrict__ bar)
{
  int gid = blockIdx.x * blockDim.x + threadIdx.x;
  int stride = gridDim.x * blockDim.x;
  for (int i = gid; i < BATCH * HID; i += stride) hb0[i] = __float2bfloat16(hid0[i]);
  for (int i = gid; i < NCH * HID;  i += stride) wob[i] = __float2bfloat16(wout[i]);
  if (gid < 4096) bar[gid] = 0u;
}

__global__ void prep_wp(const float* __restrict__ W_ih, const float* __restrict__ W_hh,
                        bf16* __restrict__ wp)
{
  int gid = blockIdx.x * blockDim.x + threadIdx.x;
  int stride = gridDim.x * blockDim.x;
  for (int i = gid; i < NP * HID; i += stride) {
    int rp = i >> 10, k = i & 1023;
    int n = rowp_to_n(rp);
    float v = W_ih[(size_t)n * 1152 + 128 + k] + W_hh[(size_t)n * 1024 + k];
    wp[i] = __float2bfloat16(v);
  }
}

__global__ void prep_xp(const float* __restrict__ inp0, const float* __restrict__ W_ih,
                        const float* __restrict__ b_ih, const float* __restrict__ b_hh,
                        float* __restrict__ xp)
{
  int b = blockIdx.x;
  const float4* ip = (const float4*)(inp0 + b * NCH);
  for (int rp = threadIdx.x; rp < NP; rp += blockDim.x) {
    int n = rowp_to_n(rp);
    const float4* wr = (const float4*)(W_ih + (size_t)n * 1152);
    float acc = b_ih[n] + b_hh[n];
    #pragma unroll 8
    for (int q = 0; q < 32; ++q) {
      float4 a = ip[q], w = wr[q];
      acc += a.x * w.x + a.y * w.y + a.z * w.z + a.w * w.w;
    }
    xp[(size_t)b * NP + rp] = acc;
  }
}

__launch_bounds__(256, 1)
__global__ void lstm_main(const bf16* __restrict__ wp, const bf16* __restrict__ wob,
                          const float* __restrict__ xp, const float* __restrict__ cell0,
                          const float* __restrict__ bout,
                          bf16* __restrict__ hb0, bf16* __restrict__ hb1,
                          float* __restrict__ out, unsigned* __restrict__ bar)
{
  __shared__ bf16 wlds[64 * HID];        // 128 KB, xor-swizzled (4 row bits)
  __shared__ float obuf[16][16][17];     // out tile x 16 buffered steps (+1 pad)
  __shared__ float opart[4][16][16];     // per-wave out-GEMM partials (split-K)
  __shared__ int s_pop[8];

  const int tid  = threadIdx.x;
  const int bx   = blockIdx.x;
  const int lane = tid & 63;
  const int wv   = tid >> 6;        // wave 0..3 (rows)
  const int bm   = bx >> 6;         // batch group 0..3 (128 rows) -- barrier group
  const int jg   = bx & 63;         // j group (16 h-cols -> 64 gate rows)
  const int wrow = bm * 128 + wv * 32;
  const int l31  = lane & 31;
  const int lhi  = lane >> 5;
  const bool low = (l31 < 16);
  const int jj   = lane & 15;
  const int jcol = jg * 16 + jj;

  // stage fused-W slice into LDS (swizzled: byte ^= (row&15)<<4)
  {
    const char* src = (const char*)(wp + (size_t)jg * 64 * HID);
    for (int it = tid; it < 8192; it += 256) {
      int r  = it >> 7;
      int kb = (it & 127) << 4;
      bf16x8 v = *(const bf16x8*)(src + r * 2048 + kb);
      *(bf16x8*)((char*)wlds + r * 2048 + (kb ^ ((r & 15) << 4))) = v;
    }
  }

  // x_part -> registers (constant acc init; C layout: col=lane&31, row=(q&3)+8*(q>>2)+4*lhi)
  f32x16 xpA, xpB;
  #pragma unroll
  for (int q = 0; q < 16; ++q) {
    int rr = (q & 3) + ((q >> 2) << 3) + (lhi << 2);
    const float* xr = xp + (size_t)(wrow + rr) * NP + jg * 64;
    xpA[q] = xr[l31];
    xpB[q] = xr[32 + l31];
  }

  // cell state -> registers. low half-lanes own rows {0-3,8-11}+4*lhi, high own +16.
  float creg[8];
  #pragma unroll
  for (int q = 0; q < 8; ++q) {
    int rr = (q & 3) + ((q >> 2) << 3) + (lhi << 2) + (low ? 0 : 16);
    creg[q] = cell0[(size_t)(wrow + rr) * HID + jcol];
  }

  const int omt = (bx >> 3) << 4;   // out-tile batch row base (subset of own bm panel)
  const int ont = (bx & 7) << 4;    // out-tile char col base (8 tiles of 16)
  const float bo = bout[ont + jj];  // jj == tid&15, reused by the reduce

  // ---- one-time census: per-(group, physical XCD) population
  const int myx = __builtin_amdgcn_s_getreg(6164) & 7;  // HW_REG_XCC_ID (id=20,off=0,sz=4)
  if (tid == 0) {
    __hip_atomic_fetch_add(bar + (size_t)(bm * 8 + myx) * 32, 1u, __ATOMIC_RELAXED, __HIP_MEMORY_SCOPE_AGENT);
    __threadfence();   // order pop-add before census-completion add
    __hip_atomic_fetch_add(bar + (size_t)32 * 32, 1u, __ATOMIC_RELEASE, __HIP_MEMORY_SCOPE_AGENT);
    int it = 0;
    while (__hip_atomic_load(bar + (size_t)32 * 32, __ATOMIC_RELAXED, __HIP_MEMORY_SCOPE_AGENT) < 256u) {
      __builtin_amdgcn_s_sleep(1);
      if ((++it & 255) == 0) __builtin_amdgcn_fence(__ATOMIC_ACQUIRE, "agent");
    }
  }
  __syncthreads();
  if (tid < 8)
    s_pop[tid] = (int)__hip_atomic_load(bar + (size_t)(bm * 8 + tid) * 32, __ATOMIC_RELAXED, __HIP_MEMORY_SCOPE_AGENT);
  __syncthreads();
  int nxg = 0, totg = 0;
  #pragma unroll
  for (int i = 0; i < 8; ++i) { nxg += (s_pop[i] != 0) ? 1 : 0; totg += s_pop[i]; }
  const bool elect = (totg == 64);   // degenerate census -> per-group all-fence fallback
  const unsigned mypop = (unsigned)s_pop[myx];
  const unsigned NF = elect ? (unsigned)nxg : 64u;
  unsigned* const xcdCnt = bar + (size_t)(40 + bm * 8 + myx) * 32;
  unsigned* const gCnt   = bar + (size_t)(80 + bm) * 32;
  unsigned* const epochX = bar + (size_t)(96 + bm * 8 + myx) * 32;

  __syncthreads();

  for (int t = 0; t <= TLEN; ++t) {
    const bf16* __restrict__ hcur = (t & 1) ? hb1 : hb0;
    bf16* __restrict__ hnxt = (t & 1) ? hb0 : hb1;

    // ---- out GEMM for step t-1 (uses h_t = hcur): split-K across 4 waves.
    if (t >= 1) {
      f32x4 oacc = {0.f, 0.f, 0.f, 0.f};
      const int kq = (lane >> 4) << 3;
      const bf16* ap = hcur + (size_t)(omt + jj) * HID + kq;
      const bf16* bp = wob + (size_t)(ont + jj) * HID + kq;
      #pragma unroll
      for (int ks = wv * 8; ks < wv * 8 + 8; ++ks) {
        bf16x8 av = *(const bf16x8*)(ap + ks * 32);
        bf16x8 bv = *(const bf16x8*)(bp + ks * 32);
        oacc = __builtin_amdgcn_mfma_f32_16x16x32_bf16(av, bv, oacc, 0, 0, 0);
      }
      #pragma unroll
      for (int q = 0; q < 4; ++q)
        opart[wv][((lane >> 4) << 2) + q][jj] = oacc[q];   // row=(l>>4)*4+q, col=jj
    }
    __syncthreads();
    if (t >= 1) {
      const int orow = tid >> 4, ocol = tid & 15;
      float s = opart[0][orow][ocol] + opart[1][orow][ocol]
              + opart[2][orow][ocol] + opart[3][orow][ocol];
      obuf[orow][ocol][(t - 1) & 15] = s + bo;
    }

    // flush 16 buffered output steps (coalesced 64B runs into [b][o][t] layout)
    if ((t & 15) == 0 && t >= 16) {
      __syncthreads();
      const int orow = tid >> 4, ocol = tid & 15;
      float* dst = out + ((size_t)(omt + orow) * NCH + (ont + ocol)) * TLEN + (t - 16);
      #pragma unroll
      for (int s = 0; s < 16; ++s) dst[s] = obuf[orow][ocol][s];
    }

    if (t == TLEN) break;

    // gates GEMM: [128x64] = x_part + h[128x1024] @ W'[64x1024]^T
    f32x16 accA = xpA, accB = xpB;
    {
      const bf16* ap = hcur + (size_t)(wrow + l31) * HID + (lhi << 3);
      const char* wb = (const char*)wlds;
      const int base0 = l31 * 2048;
      const int sxor  = (l31 & 15) << 4;   // matches 4-bit staging swizzle
      const int kb4   = lhi << 4;
      #pragma unroll 16
      for (int ks = 0; ks < 64; ++ks) {
        bf16x8 av = *(const bf16x8*)(ap + ks * 16);
        const int ko = ((ks << 5) | kb4) ^ sxor;
        bf16x8 b0 = *(const bf16x8*)(wb + base0 + ko);
        bf16x8 b1 = *(const bf16x8*)(wb + base0 + 65536 + ko);
        accA = __builtin_amdgcn_mfma_f32_32x32x16_bf16(av, b0, accA, 0, 0, 0);
        accB = __builtin_amdgcn_mfma_f32_32x32x16_bf16(av, b1, accB, 0, 0, 0);
      }
    }

    // LSTM cell update. accA cols: i (l31<16) / f (l31>=16); accB: g / o.
    float s0[16], s1[16], u0[16], u1[16];
    #pragma unroll
    for (int q = 0; q < 16; ++q) {
      s0[q] = sigm(accA[q]);                       // sig(i) on low, sig(f) on high
      float a1 = accB[q];
      float sg = sigm(low ? 2.f * a1 : a1);
      s1[q] = low ? 2.f * sg - 1.f : sg;           // tanh(g) on low, sig(o) on high
    }
    #pragma unroll
    for (int q = 0; q < 16; ++q) {
      u0[q] = __shfl_xor(s0[q], 16);
      u1[q] = __shfl_xor(s1[q], 16);
    }

    // ---- h store: packed u32, agent-scope RELAXED atomic (sc1 -> LLC).
    {
      unsigned* const h32 = (unsigned*)hnxt;
      #pragma unroll
      for (int q = 0; q < 8; ++q) {
        float fg  = low ? u0[q]         : s0[q + 8];
        float ig  = low ? s0[q] * s1[q] : u0[q + 8] * u1[q + 8];
        float og  = low ? u1[q]         : s1[q + 8];
        float cn  = fg * creg[q] + ig;
        creg[q] = cn;
        float hv = og * (2.f * sigm(2.f * cn) - 1.f);
        unsigned v = (unsigned)f2bf(hv);
        unsigned p = (unsigned)__shfl_xor((int)v, 1);
        if (!(lane & 1)) {
          int rr = (q & 3) + ((q >> 2) << 3) + (lhi << 2) + (low ? 0 : 16);
          __hip_atomic_store(&h32[((size_t)(wrow + rr) << 9) + (jcol >> 1)],
                             v | (p << 16), __ATOMIC_RELAXED, __HIP_MEMORY_SCOPE_AGENT);
        }
      }
    }

    // ---- per-group barrier: zero-wbl2 release + elected acquire ----
    asm volatile("s_waitcnt vmcnt(0)" ::: "memory");   // sc1 acks = LLC arrival
    __syncthreads();
    if (tid == 0) {
      unsigned old = __hip_atomic_fetch_add(xcdCnt, 1u, __ATOMIC_RELAXED, __HIP_MEMORY_SCOPE_AGENT);
      const bool lastx = elect && (old == mypop * (unsigned)(t + 1) - 1u);
      if (lastx) {
        // all (g,x)-mates' h stores are LLC-visible; no fence, relaxed add.
        __hip_atomic_fetch_add(gCnt, 1u, __ATOMIC_RELAXED, __HIP_MEMORY_SCOPE_AGENT);
      } else if (!elect) {
        __threadfence();   // degenerate-census fallback: conservative
        __hip_atomic_fetch_add(gCnt, 1u, __ATOMIC_RELEASE, __HIP_MEMORY_SCOPE_AGENT);
      }

      if (!elect) {
        const unsigned tgt = NF * (unsigned)(t + 1);
        int it = 0;
        while (__hip_atomic_load(gCnt, __ATOMIC_RELAXED, __HIP_MEMORY_SCOPE_AGENT) < tgt) {
          __builtin_amdgcn_s_sleep(1);
          if ((++it & 255) == 0) __builtin_amdgcn_fence(__ATOMIC_ACQUIRE, "agent");
        }
      } else if (lastx) {
        // elected: poll gCnt[g] for all this group's XCDs, ONE agent acquire
        // fence (this XCD's L2+L1 inv), publish epoch (relaxed agent, LLC).
        const unsigned tgt = (unsigned)nxg * (unsigned)(t + 1);
        int it = 0;
        while (__hip_atomic_load(gCnt, __ATOMIC_RELAXED, __HIP_MEMORY_SCOPE_AGENT) < tgt) {
          __builtin_amdgcn_s_sleep(1);
          if ((++it & 255) == 0) __builtin_amdgcn_fence(__ATOMIC_ACQUIRE, "agent");
        }
        __builtin_amdgcn_fence(__ATOMIC_ACQUIRE, "agent");  // L1+L2 inv
        __hip_atomic_store(epochX, (unsigned)(t + 1), __ATOMIC_RELAXED, __HIP_MEMORY_SCOPE_AGENT);
      } else {
        // non-elected: spin on own (group,XCD) epoch with relaxed AGENT loads.
        const unsigned want = (unsigned)(t + 1);
        int it = 0; bool ok = false;
        while (true) {
          if (__hip_atomic_load(epochX, __ATOMIC_RELAXED, __HIP_MEMORY_SCOPE_AGENT) >= want) { ok = true; break; }
          __builtin_amdgcn_s_sleep(1);
          if (++it > (1 << 18)) break;     // bounded: never hang
        }
        if (ok) {
          // XCD L2 already inv'd by elected pre-publish; drop stale L1 lines.
          asm volatile("buffer_inv" ::: "memory");
        } else {
          // timeout fallback: direct gCnt poll + full fence (conservative)
          const unsigned tgt = (unsigned)nxg * (unsigned)(t + 1);
          int it2 = 0;
          while (__hip_atomic_load(gCnt, __ATOMIC_RELAXED, __HIP_MEMORY_SCOPE_AGENT) < tgt) {
            __builtin_amdgcn_s_sleep(1);
            if ((++it2 & 255) == 0) __builtin_amdgcn_fence(__ATOMIC_ACQUIRE, "agent");
          }
          __threadfence();
        }
      }
    }
    if (!elect) {
      if (tid < 64) __builtin_amdgcn_fence(__ATOMIC_ACQUIRE, "agent");
    }
    __syncthreads();
  }
}

extern "C" void kernel_launch(void* const* d_in, const int* in_sizes, int n_in,
                              void* d_out, int out_size, void* d_ws, size_t ws_size,
                              hipStream_t stream)
{
  const float* hid0  = (const float*)d_in[0];
  const float* inp0  = (const float*)d_in[1];
  const float* cell0 = (const float*)d_in[2];
  const float* W_ih  = (const float*)d_in[3];
  const float* W_hh  = (const float*)d_in[4];
  const float* b_ih  = (const float*)d_in[5];
  const float* b_hh  = (const float*)d_in[6];
  const float* W_out = (const float*)d_in[7];
  const float* b_out = (const float*)d_in[8];
  float* out = (float*)d_out;

  char* ws = (char*)d_ws;
  bf16* wp      = (bf16*)(ws + OFF_WP);
  bf16* wob     = (bf16*)(ws + OFF_WOB);
  bf16* hb0     = (bf16*)(ws + OFF_HB0);
  bf16* hb1     = (bf16*)(ws + OFF_HB1);
  float* xp     = (float*)(ws + OFF_XP);
  unsigned* bar = (unsigned*)(ws + OFF_BAR);

  prep_misc<<<512, 256, 0, stream>>>(hid0, W_out, hb0, wob, bar);
  prep_wp<<<4096, 256, 0, stream>>>(W_ih, W_hh, wp);
  prep_xp<<<512, 256, 0, stream>>>(inp0, W_ih, b_ih, b_hh, xp);

  void* args[] = { &wp, &wob, &xp, &cell0, &b_out, &hb0, &hb1, &out, &bar };
  hipError_t e = hipLaunchCooperativeKernel(lstm_main, dim3(256), dim3(256), args, 0u, stream);
  if (e != hipSuccess) {
    lstm_main<<<dim3(256), dim3(256), 0, stream>>>(wp, wob, xp, cell0, b_out,
                                                   hb0, hb1, out, bar);
  }
}